// Round 9
// baseline (129.488 us; speedup 1.0000x reference)
//
#include <hip/hip_runtime.h>
#include <hip/hip_bf16.h>

typedef float  f32x4  __attribute__((ext_vector_type(4)));
typedef short  bf16x8 __attribute__((ext_vector_type(8)));

__device__ __forceinline__ short f2bf(float f) {
    union { __hip_bfloat16 h; short s; } u;
    u.h = __float2bfloat16(f);
    return u.s;
}

__device__ __forceinline__ void gload_lds16(const void* g, void* l) {
    __builtin_amdgcn_global_load_lds(
        (const __attribute__((address_space(1))) unsigned int*)g,
        (__attribute__((address_space(3))) unsigned int*)l, 16, 0, 0);
}

__device__ __forceinline__ void nt_load8(const float* p, float* dst) {
    const f32x4* vp = reinterpret_cast<const f32x4*>(p);
    f32x4 a = __builtin_nontemporal_load(vp);
    f32x4 b = __builtin_nontemporal_load(vp + 1);
    *reinterpret_cast<f32x4*>(dst)     = a;
    *reinterpret_cast<f32x4*>(dst + 4) = b;
}

// ---------------- K1: transpose x -> xt bf16 [b][p][c]; partial g; 4-part xsum ----------
__global__ __launch_bounds__(256) void transpose_kernel(const float* __restrict__ x,
                                                        short* __restrict__ xt,
                                                        float* __restrict__ gpart,
                                                        float* __restrict__ xsump) {
    const int pchunk = blockIdx.x;
    const int cchunk = blockIdx.y;
    const int c0 = cchunk * 64;
    const int b  = blockIdx.z;
    const int tid = threadIdx.x;
    const int cpair = tid >> 3;      // 0..31 -> c = c0 + 2*cpair + {0,1}
    const int poct  = tid & 7;       // p = poct*8 + e
    const int p0 = pchunk * 64;

    __shared__ unsigned int tile[64 * 32];   // 8 KB
    __shared__ float xred[4 * 64];           // 1 KB

    const float* rowA = x + ((size_t)(b * 256 + c0 + 2 * cpair)) * 4096 + p0 + poct * 8;
    const float* rowB = rowA + 4096;
    float av[8], bv[8];
    nt_load8(rowA, av);
    nt_load8(rowB, bv);

    // per-channel sums for g
    float sA = 0.f, sB = 0.f;
    #pragma unroll
    for (int e = 0; e < 8; ++e) { sA += av[e]; sB += bv[e]; }
    sA += __shfl_xor(sA, 1, 64); sA += __shfl_xor(sA, 2, 64); sA += __shfl_xor(sA, 4, 64);
    sB += __shfl_xor(sB, 1, 64); sB += __shfl_xor(sB, 2, 64); sB += __shfl_xor(sB, 4, 64);
    if (poct == 0) {
        gpart[((size_t)(b * 256 + c0 + 2 * cpair)) * 64 + pchunk] = sA;
        gpart[((size_t)(b * 256 + c0 + 2 * cpair + 1)) * 64 + pchunk] = sB;
    }

    // per-p xsum partial: wave-reduce 16 channels (lane bits 3..5)
    float xs[8];
    #pragma unroll
    for (int e = 0; e < 8; ++e) {
        float v = av[e] + bv[e];
        v += __shfl_xor(v, 8, 64);
        v += __shfl_xor(v, 16, 64);
        v += __shfl_xor(v, 32, 64);
        xs[e] = v;
    }
    if ((tid & 56) == 0) {   // lanes 0..7 of each wave
        int wv = tid >> 6;
        #pragma unroll
        for (int e = 0; e < 8; ++e) xred[wv * 64 + poct * 8 + e] = xs[e];
    }

    const int s = cpair >> 2, w = cpair & 3;
    #pragma unroll
    for (int e = 0; e < 8; ++e) {
        int p = poct * 8 + e;
        unsigned int u = (unsigned int)(unsigned short)f2bf(av[e]) |
                         ((unsigned int)(unsigned short)f2bf(bv[e]) << 16);
        tile[p * 32 + ((s ^ poct) << 2) + w] = u;
    }
    __syncthreads();

    // cross-wave xsum combine: one part per c-chunk
    if (tid < 64) {
        float v = xred[tid] + xred[64 + tid] + xred[128 + tid] + xred[192 + tid];
        xsump[((size_t)(cchunk * 32 + b)) * 4096 + p0 + tid] = v;
    }

    const int so = tid & 7;
    #pragma unroll
    for (int h = 0; h < 2; ++h) {
        int p = (tid >> 3) + h * 32;
        int sp = so ^ ((p >> 3) & 7);
        uint4 v = *reinterpret_cast<const uint4*>(&tile[p * 32 + sp * 4]);
        *reinterpret_cast<uint4*>(xt + ((size_t)b * 4096 + p0 + p) * 256 + c0 + so * 8) = v;
    }
}

// ---------------- K3': per-block prep (g,s,t,vq from gpart) + cmap0/txs ----------------
// grid (16, 33): y<32 -> b=y, x = p-chunk; y==32 -> convert w2l seg x to bf16.
__global__ __launch_bounds__(256) void prep_cmap0_kernel(
    const short* __restrict__ xt, const float* __restrict__ gpart,
    const float* __restrict__ w1l, const float* __restrict__ w1g1,
    const float* __restrict__ w1g2, const float* __restrict__ w2l,
    const float* __restrict__ w2g, const float* __restrict__ xsump,
    float* __restrict__ s_out, short* __restrict__ w2l_bf,
    float* __restrict__ cmap0, float* __restrict__ txs) {
    const int b = blockIdx.y;
    const int tid = threadIdx.x;
    if (b >= 32) {  // convert w2l (256x256) to bf16; 16 blocks, seg = blockIdx.x
        int seg = blockIdx.x;
        const float* src = w2l + seg * 4096;
        short* dst = w2l_bf + seg * 4096;
        #pragma unroll
        for (int it = 0; it < 4; ++it) {
            float4 v = *reinterpret_cast<const float4*>(src + it * 1024 + tid * 4);
            short4 o;
            o.x = f2bf(v.x); o.y = f2bf(v.y); o.z = f2bf(v.z); o.w = f2bf(v.w);
            *reinterpret_cast<short4*>(dst + it * 1024 + tid * 4) = o;
        }
        return;
    }
    __shared__ float gs[256];
    __shared__ float zs[8];
    __shared__ float ss[256];
    __shared__ float red[4];
    __shared__ float vs[256];
    {
        const float4* gp = reinterpret_cast<const float4*>(gpart + (size_t)(b * 256 + tid) * 64);
        float acc = 0.f;
        #pragma unroll
        for (int j = 0; j < 16; ++j) { float4 v = gp[j]; acc += v.x + v.y + v.z + v.w; }
        gs[tid] = acc * (1.0f / 4096.0f);
    }
    __syncthreads();
    if (tid < 8) {
        float z = 0.f;
        for (int i = 0; i < 32; ++i) z += gs[tid * 32 + i] * w1g1[tid * 32 + i];
        zs[tid] = z;
    }
    __syncthreads();
    {
        int grp = tid >> 5, o = tid & 31;
        float local = 0.f;
        #pragma unroll 4
        for (int i = 0; i < 32; ++i) local += gs[grp * 32 + i] * w1l[grp * 1024 + o * 32 + i];
        float glob = 0.f;
        #pragma unroll
        for (int gg = 0; gg < 8; ++gg) glob += zs[gg] * w1g2[tid * 8 + gg];
        float sv = 1.0f / (1.0f + expf(-(local + glob)));
        ss[tid] = sv;
        if (blockIdx.x == 0) s_out[b * 256 + tid] = sv;
        float tv = sv * w2g[tid];
        #pragma unroll
        for (int off = 32; off; off >>= 1) tv += __shfl_down(tv, off, 64);
        if ((tid & 63) == 0) red[tid >> 6] = tv;
    }
    __syncthreads();
    const float tb = red[0] + red[1] + red[2] + red[3];
    {
        float v = 0.f;
        for (int o2 = 0; o2 < 256; ++o2) v += ss[o2] * w2l[o2 * 256 + tid];
        vs[tid] = v * (1.0f / 256.0f);
    }
    __syncthreads();

    // main: cmap0 = vs·xt(bf16) + tb*xsum(exact); txs = tb*xsum
    const int p = blockIdx.x * 256 + tid;
    const uint4* row = reinterpret_cast<const uint4*>(xt + ((size_t)b * 4096 + p) * 256);
    float acc = 0.f;
    #pragma unroll 8
    for (int it = 0; it < 32; ++it) {
        uint4 u = row[it];
        const unsigned int* uw = reinterpret_cast<const unsigned int*>(&u);
        #pragma unroll
        for (int j = 0; j < 4; ++j) {
            unsigned int wrd = uw[j];
            union { unsigned int u; float f; } lo, hi;
            lo.u = wrd << 16;
            hi.u = wrd & 0xffff0000u;
            acc += lo.f * vs[it * 8 + 2 * j] + hi.f * vs[it * 8 + 2 * j + 1];
        }
    }
    float xsv = 0.f;
    #pragma unroll
    for (int part = 0; part < 4; ++part)
        xsv += xsump[((size_t)(part * 32 + b)) * 4096 + p];
    float tx = tb * xsv;
    cmap0[b * 4096 + p] = acc + tx;
    txs[b * 4096 + p] = tx;
}

// ---------------- K5: GEMM + in-kernel conv epilogue. BM=256 x BN=64, BK=32, 4 waves,
// double-buffered, 40 KiB LDS -> 4 blocks/CU. 2-phase counted-vmcnt pipeline (5 loads/thr).
// Slot swizzle f(r)=(r^(r>>2))&3: store stays gload_lds lane-linear, reads 2-way (free).
__global__ __launch_bounds__(256, 4) void gemm_epi_kernel(
    const short* __restrict__ xt, const short* __restrict__ w2l_bf,
    const float* __restrict__ s, const float* __restrict__ txs,
    const float* __restrict__ cmap0, const float* __restrict__ w9a,
    const float* __restrict__ w9b, float* __restrict__ out) {
    const int b  = blockIdx.z;
    const int r  = blockIdx.x;          // image row; p0 = r*64
    const int p0 = r * 64;
    const int tid  = threadIdx.x;
    const int lane = tid & 63;
    const int w    = tid >> 6;          // wave 0..3
    const int wm = w >> 1, wn = w & 1;  // 2x2 wave grid: 128 o x 32 p each

    __shared__ short Alds[2][256 * 32];    // 2 x 16 KiB
    __shared__ short Xlds[2][64 * 32];     // 2 x 4 KiB

    const int l2 = lane >> 2;           // 0..15

    f32x4 acc[8][2] = {};

    auto STAGE = [&](int bi, int ks) {
        #pragma unroll
        for (int j = 0; j < 4; ++j) {
            int row = j * 64 + w * 16 + l2;
            int sig = (lane & 3) ^ ((row ^ (row >> 2)) & 3);
            gload_lds16(w2l_bf + (size_t)row * 256 + ks + sig * 8,
                        (char*)(&Alds[bi][0]) + j * 4096 + w * 1024);
        }
        {
            int prow = w * 16 + l2;
            int sig = (lane & 3) ^ ((prow ^ (prow >> 2)) & 3);
            gload_lds16(xt + ((size_t)b * 4096 + p0 + prow) * 256 + ks + sig * 8,
                        (char*)(&Xlds[bi][0]) + w * 1024);
        }
    };

    STAGE(0, 0);
    #pragma unroll
    for (int t = 0; t < 8; ++t) {
        const int bi = t & 1;
        if (t < 7) {
            STAGE(bi ^ 1, (t + 1) * 32);
            asm volatile("s_waitcnt vmcnt(5)" ::: "memory");  // own current-tile loads done
        } else {
            asm volatile("s_waitcnt vmcnt(0)" ::: "memory");
        }
        __builtin_amdgcn_s_barrier();                         // all waves' loads visible
        asm volatile("" ::: "memory");
        bf16x8 bfr[2];
        #pragma unroll
        for (int n = 0; n < 2; ++n) {
            int p = wn * 32 + n * 16 + (lane & 15);
            int sl = (lane >> 4) ^ ((p ^ (p >> 2)) & 3);
            bfr[n] = *reinterpret_cast<const bf16x8*>(
                (char*)(&Xlds[bi][0]) + p * 64 + sl * 16);
        }
        #pragma unroll
        for (int mh = 0; mh < 2; ++mh) {
            bf16x8 af[4];
            #pragma unroll
            for (int i = 0; i < 4; ++i) {
                int o = wm * 128 + (mh * 4 + i) * 16 + (lane & 15);
                int sl = (lane >> 4) ^ ((o ^ (o >> 2)) & 3);
                af[i] = *reinterpret_cast<const bf16x8*>(
                    (char*)(&Alds[bi][0]) + o * 64 + sl * 16);
            }
            #pragma unroll
            for (int i = 0; i < 4; ++i)
                #pragma unroll
                for (int n = 0; n < 2; ++n)
                    acc[mh * 4 + i][n] = __builtin_amdgcn_mfma_f32_16x16x32_bf16(
                        af[i], bfr[n], acc[mh * 4 + i][n], 0, 0, 0);
        }
        asm volatile("" ::: "memory");
        __builtin_amdgcn_s_barrier();                         // safe to restage this buffer
    }

    // ---- in-kernel cmap row: conv1 -> sigmoid -> conv2 on 5 staged cmap0 rows ----
    float wa[9], wb[9];
    #pragma unroll
    for (int i = 0; i < 9; ++i) { wa[i] = w9a[i]; wb[i] = w9b[i]; }
    __syncthreads();
    float* csc  = (float*)&Alds[0][0];   // 5*64
    float* midl = csc + 320;             // 3*64
    float* cmsl = midl + 192;            // 64
    for (int idx = tid; idx < 320; idx += 256) {
        int i5 = idx >> 6, cc = idx & 63;
        int rr = r - 2 + i5;
        csc[idx] = (rr >= 0 && rr < 64) ? cmap0[(size_t)b * 4096 + rr * 64 + cc] : 0.f;
    }
    __syncthreads();
    if (tid < 192) {
        int i3 = tid >> 6, cc = tid & 63;
        int rm = r - 1 + i3;
        float a = 0.f;
        if (rm >= 0 && rm < 64) {
            #pragma unroll
            for (int dy = 0; dy < 3; ++dy)
                #pragma unroll
                for (int dx = -1; dx <= 1; ++dx) {
                    int c2 = cc + dx;
                    if (c2 >= 0 && c2 < 64)
                        a += csc[(i3 + dy) * 64 + c2] * wa[dy * 3 + dx + 1];
                }
            a = 1.0f / (1.0f + expf(-a));
        }
        midl[tid] = a;
    }
    __syncthreads();
    if (tid < 64) {
        float a = 0.f;
        #pragma unroll
        for (int i3 = 0; i3 < 3; ++i3)
            #pragma unroll
            for (int dx = -1; dx <= 1; ++dx) {
                int c2 = tid + dx;
                if (c2 >= 0 && c2 < 64)
                    a += midl[i3 * 64 + c2] * wb[i3 * 3 + dx + 1];
            }
        cmsl[tid] = a;
    }
    __syncthreads();

    #pragma unroll
    for (int n = 0; n < 2; ++n) {
        int pc = wn * 32 + n * 16 + (lane & 15);   // p - p0
        int p = p0 + pc;
        float cm = cmsl[pc];
        float tx = txs[b * 4096 + p];
        #pragma unroll
        for (int m = 0; m < 8; ++m) {
            #pragma unroll
            for (int q = 0; q < 4; ++q) {
                int o = wm * 128 + m * 16 + (lane >> 4) * 4 + q;
                float sv = s[b * 256 + o];
                float yv = (sv * acc[m][n][q] + tx) * cm;
                __builtin_nontemporal_store(yv, &out[((size_t)b * 256 + o) * 4096 + p]);
            }
        }
    }
}

extern "C" void kernel_launch(void* const* d_in, const int* in_sizes, int n_in,
                              void* d_out, int out_size, void* d_ws, size_t ws_size,
                              hipStream_t stream) {
    const float* x       = (const float*)d_in[0];
    const float* w1l     = (const float*)d_in[1];
    const float* w1g1    = (const float*)d_in[2];
    const float* w1g2    = (const float*)d_in[3];
    const float* w2l     = (const float*)d_in[4];
    const float* w2g     = (const float*)d_in[5];
    const float* conv1_w = (const float*)d_in[6];
    const float* conv2_w = (const float*)d_in[7];
    float* out = (float*)d_out;

    float* wsf    = (float*)d_ws;
    float* s      = wsf;                        // 8192
    float* cmap0  = wsf + 8192;                 // 131072
    float* txs    = wsf + 139264;               // 131072
    float* gpart  = wsf + 270336;               // 524288
    float* xsump  = wsf + 794624;               // 4*32*4096 = 524288
    short* w2l_bf = (short*)(wsf + 1318912);    // 65536 shorts
    short* xt     = (short*)(wsf + 1351680);    // 33554432 shorts (64 MiB)

    transpose_kernel<<<dim3(64, 4, 32), 256, 0, stream>>>(x, xt, gpart, xsump);
    prep_cmap0_kernel<<<dim3(16, 33), 256, 0, stream>>>(
        xt, gpart, w1l, w1g1, w1g2, w2l, w2g, xsump, s, w2l_bf, cmap0, txs);
    gemm_epi_kernel<<<dim3(64, 1, 32), 256, 0, stream>>>(
        xt, w2l_bf, s, txs, cmap0, conv1_w, conv2_w, out);
}

// Round 10
// 118.620 us; speedup vs baseline: 1.0916x; 1.0916x over previous
//
#include <hip/hip_runtime.h>
#include <hip/hip_bf16.h>

typedef float  f32x4  __attribute__((ext_vector_type(4)));
typedef short  bf16x8 __attribute__((ext_vector_type(8)));

__device__ __forceinline__ short f2bf(float f) {
    union { __hip_bfloat16 h; short s; } u;
    u.h = __float2bfloat16(f);
    return u.s;
}

__device__ __forceinline__ void gload_lds16(const void* g, void* l) {
    __builtin_amdgcn_global_load_lds(
        (const __attribute__((address_space(1))) unsigned int*)g,
        (__attribute__((address_space(3))) unsigned int*)l, 16, 0, 0);
}

__device__ __forceinline__ void nt_load8(const float* p, float* dst) {
    const f32x4* vp = reinterpret_cast<const f32x4*>(p);
    f32x4 a = __builtin_nontemporal_load(vp);
    f32x4 b = __builtin_nontemporal_load(vp + 1);
    *reinterpret_cast<f32x4*>(dst)     = a;
    *reinterpret_cast<f32x4*>(dst + 4) = b;
}

// ---------------- K1: transpose x -> xt bf16 [b][p][c]; partial g; 4-part xsum ----------
__global__ __launch_bounds__(256) void transpose_kernel(const float* __restrict__ x,
                                                        short* __restrict__ xt,
                                                        float* __restrict__ gpart,
                                                        float* __restrict__ xsump) {
    const int pchunk = blockIdx.x;
    const int cchunk = blockIdx.y;
    const int c0 = cchunk * 64;
    const int b  = blockIdx.z;
    const int tid = threadIdx.x;
    const int cpair = tid >> 3;      // 0..31 -> c = c0 + 2*cpair + {0,1}
    const int poct  = tid & 7;       // p = poct*8 + e
    const int p0 = pchunk * 64;

    __shared__ unsigned int tile[64 * 32];   // 8 KB
    __shared__ float xred[4 * 64];           // 1 KB

    const float* rowA = x + ((size_t)(b * 256 + c0 + 2 * cpair)) * 4096 + p0 + poct * 8;
    const float* rowB = rowA + 4096;
    float av[8], bv[8];
    nt_load8(rowA, av);
    nt_load8(rowB, bv);

    // per-channel sums for g
    float sA = 0.f, sB = 0.f;
    #pragma unroll
    for (int e = 0; e < 8; ++e) { sA += av[e]; sB += bv[e]; }
    sA += __shfl_xor(sA, 1, 64); sA += __shfl_xor(sA, 2, 64); sA += __shfl_xor(sA, 4, 64);
    sB += __shfl_xor(sB, 1, 64); sB += __shfl_xor(sB, 2, 64); sB += __shfl_xor(sB, 4, 64);
    if (poct == 0) {
        gpart[((size_t)(b * 256 + c0 + 2 * cpair)) * 64 + pchunk] = sA;
        gpart[((size_t)(b * 256 + c0 + 2 * cpair + 1)) * 64 + pchunk] = sB;
    }

    // per-p xsum partial: wave-reduce 16 channels (lane bits 3..5)
    float xs[8];
    #pragma unroll
    for (int e = 0; e < 8; ++e) {
        float v = av[e] + bv[e];
        v += __shfl_xor(v, 8, 64);
        v += __shfl_xor(v, 16, 64);
        v += __shfl_xor(v, 32, 64);
        xs[e] = v;
    }
    if ((tid & 56) == 0) {   // lanes 0..7 of each wave
        int wv = tid >> 6;
        #pragma unroll
        for (int e = 0; e < 8; ++e) xred[wv * 64 + poct * 8 + e] = xs[e];
    }

    const int s = cpair >> 2, w = cpair & 3;
    #pragma unroll
    for (int e = 0; e < 8; ++e) {
        int p = poct * 8 + e;
        unsigned int u = (unsigned int)(unsigned short)f2bf(av[e]) |
                         ((unsigned int)(unsigned short)f2bf(bv[e]) << 16);
        tile[p * 32 + ((s ^ poct) << 2) + w] = u;
    }
    __syncthreads();

    // cross-wave xsum combine: one part per c-chunk
    if (tid < 64) {
        float v = xred[tid] + xred[64 + tid] + xred[128 + tid] + xred[192 + tid];
        xsump[((size_t)(cchunk * 32 + b)) * 4096 + p0 + tid] = v;
    }

    const int so = tid & 7;
    #pragma unroll
    for (int h = 0; h < 2; ++h) {
        int p = (tid >> 3) + h * 32;
        int sp = so ^ ((p >> 3) & 7);
        uint4 v = *reinterpret_cast<const uint4*>(&tile[p * 32 + sp * 4]);
        *reinterpret_cast<uint4*>(xt + ((size_t)b * 4096 + p0 + p) * 256 + c0 + so * 8) = v;
    }
}

// ---------------- K3': per-block prep (g,s,t,vq from gpart) + cmap0/txs ----------------
// grid (16, 33): y<32 -> b=y, x = p-chunk; y==32 -> convert w2l seg x to bf16.
__global__ __launch_bounds__(256) void prep_cmap0_kernel(
    const short* __restrict__ xt, const float* __restrict__ gpart,
    const float* __restrict__ w1l, const float* __restrict__ w1g1,
    const float* __restrict__ w1g2, const float* __restrict__ w2l,
    const float* __restrict__ w2g, const float* __restrict__ xsump,
    float* __restrict__ s_out, short* __restrict__ w2l_bf,
    float* __restrict__ cmap0, float* __restrict__ txs) {
    const int b = blockIdx.y;
    const int tid = threadIdx.x;
    if (b >= 32) {  // convert w2l (256x256) to bf16; 16 blocks, seg = blockIdx.x
        int seg = blockIdx.x;
        const float* src = w2l + seg * 4096;
        short* dst = w2l_bf + seg * 4096;
        #pragma unroll
        for (int it = 0; it < 4; ++it) {
            float4 v = *reinterpret_cast<const float4*>(src + it * 1024 + tid * 4);
            short4 o;
            o.x = f2bf(v.x); o.y = f2bf(v.y); o.z = f2bf(v.z); o.w = f2bf(v.w);
            *reinterpret_cast<short4*>(dst + it * 1024 + tid * 4) = o;
        }
        return;
    }
    __shared__ float gs[256];
    __shared__ float zs[8];
    __shared__ float ss[256];
    __shared__ float red[4];
    __shared__ float vs[256];
    {
        const float4* gp = reinterpret_cast<const float4*>(gpart + (size_t)(b * 256 + tid) * 64);
        float acc = 0.f;
        #pragma unroll
        for (int j = 0; j < 16; ++j) { float4 v = gp[j]; acc += v.x + v.y + v.z + v.w; }
        gs[tid] = acc * (1.0f / 4096.0f);
    }
    __syncthreads();
    if (tid < 8) {
        float z = 0.f;
        for (int i = 0; i < 32; ++i) z += gs[tid * 32 + i] * w1g1[tid * 32 + i];
        zs[tid] = z;
    }
    __syncthreads();
    {
        int grp = tid >> 5, o = tid & 31;
        float local = 0.f;
        #pragma unroll 4
        for (int i = 0; i < 32; ++i) local += gs[grp * 32 + i] * w1l[grp * 1024 + o * 32 + i];
        float glob = 0.f;
        #pragma unroll
        for (int gg = 0; gg < 8; ++gg) glob += zs[gg] * w1g2[tid * 8 + gg];
        float sv = 1.0f / (1.0f + expf(-(local + glob)));
        ss[tid] = sv;
        if (blockIdx.x == 0) s_out[b * 256 + tid] = sv;
        float tv = sv * w2g[tid];
        #pragma unroll
        for (int off = 32; off; off >>= 1) tv += __shfl_down(tv, off, 64);
        if ((tid & 63) == 0) red[tid >> 6] = tv;
    }
    __syncthreads();
    const float tb = red[0] + red[1] + red[2] + red[3];
    {
        float v = 0.f;
        for (int o2 = 0; o2 < 256; ++o2) v += ss[o2] * w2l[o2 * 256 + tid];
        vs[tid] = v * (1.0f / 256.0f);
    }
    __syncthreads();

    // main: cmap0 = vs·xt(bf16) + tb*xsum(exact); txs = tb*xsum
    const int p = blockIdx.x * 256 + tid;
    const uint4* row = reinterpret_cast<const uint4*>(xt + ((size_t)b * 4096 + p) * 256);
    float acc = 0.f;
    #pragma unroll 8
    for (int it = 0; it < 32; ++it) {
        uint4 u = row[it];
        const unsigned int* uw = reinterpret_cast<const unsigned int*>(&u);
        #pragma unroll
        for (int j = 0; j < 4; ++j) {
            unsigned int wrd = uw[j];
            union { unsigned int u; float f; } lo, hi;
            lo.u = wrd << 16;
            hi.u = wrd & 0xffff0000u;
            acc += lo.f * vs[it * 8 + 2 * j] + hi.f * vs[it * 8 + 2 * j + 1];
        }
    }
    float xsv = 0.f;
    #pragma unroll
    for (int part = 0; part < 4; ++part)
        xsv += xsump[((size_t)(part * 32 + b)) * 4096 + p];
    float tx = tb * xsv;
    cmap0[b * 4096 + p] = acc + tx;
    txs[b * 4096 + p] = tx;
}

// ---------------- K5: GEMM + in-kernel conv epilogue. BM=256 x BN=64, BK=64, 8 waves.
// 2-phase counted-vmcnt pipeline; epilogue computes its own cmap row (conv1+sig+conv2)
// from 5 prefetched cmap0 rows; nontemporal out stores.
__global__ __launch_bounds__(512) void gemm_epi_kernel(
    const short* __restrict__ xt, const short* __restrict__ w2l_bf,
    const float* __restrict__ s, const float* __restrict__ txs,
    const float* __restrict__ cmap0, const float* __restrict__ w9a,
    const float* __restrict__ w9b, float* __restrict__ out) {
    const int b  = blockIdx.z;
    const int r  = blockIdx.x;          // image row; p0 = r*64
    const int p0 = r * 64;
    const int tid  = threadIdx.x;
    const int lane = tid & 63;
    const int w    = tid >> 6;          // wave 0..7
    const int wm = w >> 1, wn = w & 1;  // 4x2 wave grid: 64 o x 32 p each

    __shared__ short Alds[2][256 * 64];    // 2 x 32 KB
    __shared__ short Xlds[2][64 * 64];     // 2 x 8 KB

    const int sl   = (lane & 7) ^ (lane >> 3);  // pre-swizzled source slot
    const int lrow = lane >> 3;

    // ---- prefetches (L2-hot; complete long before use) ----
    float wa[9], wb[9];
    #pragma unroll
    for (int i = 0; i < 9; ++i) { wa[i] = w9a[i]; wb[i] = w9b[i]; }
    float c0v = 0.f;
    if (tid < 320) {
        int i5 = tid >> 6, cc = tid & 63;
        int rr = r - 2 + i5;
        if (rr >= 0 && rr < 64) c0v = cmap0[(size_t)b * 4096 + rr * 64 + cc];
    }
    float txr[2], sv[4][4];
    #pragma unroll
    for (int n = 0; n < 2; ++n) {
        int p = p0 + wn * 32 + n * 16 + (lane & 15);
        txr[n] = txs[b * 4096 + p];
    }
    #pragma unroll
    for (int m = 0; m < 4; ++m)
        #pragma unroll
        for (int q = 0; q < 4; ++q)
            sv[m][q] = s[b * 256 + wm * 64 + m * 16 + (lane >> 4) * 4 + q];

    f32x4 acc[4][2] = {};

    auto STAGE = [&](int bi, int ks) {
        #pragma unroll
        for (int j = 0; j < 4; ++j) {
            int chunk = w * 4 + j;
            int row = chunk * 8 + lrow;
            gload_lds16(w2l_bf + (size_t)row * 256 + ks + sl * 8,
                        (char*)(&Alds[bi][0]) + chunk * 1024);
        }
        int prow = w * 8 + lrow;
        gload_lds16(xt + ((size_t)b * 4096 + p0 + prow) * 256 + ks + sl * 8,
                    (char*)(&Xlds[bi][0]) + w * 1024);
    };

    STAGE(0, 0);
    #pragma unroll
    for (int t = 0; t < 4; ++t) {
        const int bi = t & 1;
        if (t < 3) {
            STAGE(bi ^ 1, (t + 1) * 64);
            asm volatile("s_waitcnt vmcnt(5)" ::: "memory");  // own current-tile loads done
        } else {
            asm volatile("s_waitcnt vmcnt(0)" ::: "memory");
        }
        __builtin_amdgcn_s_barrier();                         // all waves' loads visible
        asm volatile("" ::: "memory");
        #pragma unroll
        for (int kk = 0; kk < 2; ++kk) {
            bf16x8 af[4], bfr[2];
            const int ss = kk * 4 + (lane >> 4);
            #pragma unroll
            for (int m = 0; m < 4; ++m) {
                int o = wm * 64 + m * 16 + (lane & 15);
                af[m] = *reinterpret_cast<const bf16x8*>(
                    (char*)(&Alds[bi][0]) + o * 128 + ((ss ^ (lane & 7)) * 16));
            }
            #pragma unroll
            for (int n = 0; n < 2; ++n) {
                int p = wn * 32 + n * 16 + (lane & 15);
                bfr[n] = *reinterpret_cast<const bf16x8*>(
                    (char*)(&Xlds[bi][0]) + p * 128 + ((ss ^ (lane & 7)) * 16));
            }
            #pragma unroll
            for (int m = 0; m < 4; ++m)
                #pragma unroll
                for (int n = 0; n < 2; ++n)
                    acc[m][n] = __builtin_amdgcn_mfma_f32_16x16x32_bf16(af[m], bfr[n], acc[m][n], 0, 0, 0);
        }
        asm volatile("" ::: "memory");
        __builtin_amdgcn_s_barrier();                         // safe to restage this buffer
    }

    // ---- in-kernel cmap row: conv1 -> sigmoid -> conv2 on 5 staged cmap0 rows ----
    __syncthreads();
    float* csc  = (float*)&Alds[0][0];   // 5*64
    float* midl = csc + 320;             // 3*64
    float* cmsl = midl + 192;            // 64
    if (tid < 320) csc[tid] = c0v;
    __syncthreads();
    if (tid < 192) {
        int i3 = tid >> 6, cc = tid & 63;
        int rm = r - 1 + i3;
        float a = 0.f;
        if (rm >= 0 && rm < 64) {
            #pragma unroll
            for (int dy = 0; dy < 3; ++dy)
                #pragma unroll
                for (int dx = -1; dx <= 1; ++dx) {
                    int c2 = cc + dx;
                    if (c2 >= 0 && c2 < 64)
                        a += csc[(i3 + dy) * 64 + c2] * wa[dy * 3 + dx + 1];
                }
            a = 1.0f / (1.0f + expf(-a));
        }
        midl[tid] = a;
    }
    __syncthreads();
    if (tid < 64) {
        float a = 0.f;
        #pragma unroll
        for (int i3 = 0; i3 < 3; ++i3)
            #pragma unroll
            for (int dx = -1; dx <= 1; ++dx) {
                int c2 = tid + dx;
                if (c2 >= 0 && c2 < 64)
                    a += midl[i3 * 64 + c2] * wb[i3 * 3 + dx + 1];
            }
        cmsl[tid] = a;
    }
    __syncthreads();

    #pragma unroll
    for (int n = 0; n < 2; ++n) {
        int pc = wn * 32 + n * 16 + (lane & 15);   // p - p0
        int p = p0 + pc;
        float cm = cmsl[pc];
        #pragma unroll
        for (int m = 0; m < 4; ++m) {
            #pragma unroll
            for (int q = 0; q < 4; ++q) {
                int o = wm * 64 + m * 16 + (lane >> 4) * 4 + q;
                float yv = (sv[m][q] * acc[m][n][q] + txr[n]) * cm;
                __builtin_nontemporal_store(yv, &out[((size_t)b * 256 + o) * 4096 + p]);
            }
        }
    }
}

extern "C" void kernel_launch(void* const* d_in, const int* in_sizes, int n_in,
                              void* d_out, int out_size, void* d_ws, size_t ws_size,
                              hipStream_t stream) {
    const float* x       = (const float*)d_in[0];
    const float* w1l     = (const float*)d_in[1];
    const float* w1g1    = (const float*)d_in[2];
    const float* w1g2    = (const float*)d_in[3];
    const float* w2l     = (const float*)d_in[4];
    const float* w2g     = (const float*)d_in[5];
    const float* conv1_w = (const float*)d_in[6];
    const float* conv2_w = (const float*)d_in[7];
    float* out = (float*)d_out;

    float* wsf    = (float*)d_ws;
    float* s      = wsf;                        // 8192
    float* cmap0  = wsf + 8192;                 // 131072
    float* txs    = wsf + 139264;               // 131072
    float* gpart  = wsf + 270336;               // 524288
    float* xsump  = wsf + 794624;               // 4*32*4096 = 524288
    short* w2l_bf = (short*)(wsf + 1318912);    // 65536 shorts
    short* xt     = (short*)(wsf + 1351680);    // 33554432 shorts (64 MiB)

    transpose_kernel<<<dim3(64, 4, 32), 256, 0, stream>>>(x, xt, gpart, xsump);
    prep_cmap0_kernel<<<dim3(16, 33), 256, 0, stream>>>(
        xt, gpart, w1l, w1g1, w1g2, w2l, w2g, xsump, s, w2l_bf, cmap0, txs);
    gemm_epi_kernel<<<dim3(64, 1, 32), 512, 0, stream>>>(
        xt, w2l_bf, s, txs, cmap0, conv1_w, conv2_w, out);
}